// Round 7
// baseline (293.125 us; speedup 1.0000x reference)
//
#include <hip/hip_runtime.h>

// ScaledDotProductAttention: context = softmax(relu(Q K^T) @ R / 8) @ V
// B=8, N=2048, D=64. R = (1+e)/(1+exp(1-dist)), shared across batch.
//
// ws layout (needs ~91.5 MB):
//   [0,   64MB)  Ph  : fp16 relu(QK^T)*0.125, [B][N][N]
//   [64MB,72MB)  RhT : fp16 R^T, [j][m]
//   [72MB,74MB)  VhT : fp16 V^T, [B][64][N]
//   [74MB,90MB)  Op  : fp16 partial O, [2048 wg][64][64]
//   [90MB,...)   mp, lp : fp32 partial rowmax/rowsum, [2048][64] each

typedef _Float16 f16;
typedef _Float16 f16x8 __attribute__((ext_vector_type(8)));
typedef float    f32x4 __attribute__((ext_vector_type(4)));

#define AS1C(p) ((const __attribute__((address_space(1))) void*)(p))
#define AS3(p)  ((__attribute__((address_space(3))) void*)(p))

__device__ __forceinline__ f16x8 cvt_f16x8(float4 a, float4 b){
  f16x8 v;
  v[0]=(f16)a.x; v[1]=(f16)a.y; v[2]=(f16)a.z; v[3]=(f16)a.w;
  v[4]=(f16)b.x; v[5]=(f16)b.y; v[6]=(f16)b.z; v[7]=(f16)b.w;
  return v;
}

// ---------------- kernel 1: fused prep + QK^T --------------------------------
// Flat grid 3328: [0,2048) QK tiles; [2048,3072) rescale-transpose tiles;
// [3072,3328) V-transpose tiles. One launch instead of three.
__launch_bounds__(256, 2)
__global__ void k_qk(const float* __restrict__ Q, const float* __restrict__ Km,
                     const float* __restrict__ V, const float* __restrict__ Dm,
                     f16* __restrict__ Ph, f16* __restrict__ RhT,
                     f16* __restrict__ VhT){
  __shared__ __align__(16) char shm[36864];
  const int bid = blockIdx.x;
  const int t = threadIdx.x;

  if (bid >= 2048){
    f16* tl = (f16*)shm;                         // [64][65]
    const int c = t & 63, g = t >> 6;
    if (bid < 3072){                             // RhT[j][m] = rescale(D[m][j])
      const int pid = bid - 2048;
      const int k0 = (pid & 31)*64, m0 = (pid >> 5)*64;
#pragma unroll
      for (int i=0;i<16;++i){
        int k = g*16 + i;
        float d = Dm[(size_t)(k0 + k)*2048 + m0 + c];
        tl[k*65 + c] = (f16)(3.7182818284590452f / (1.0f + __expf(1.0f - d)));
      }
      __syncthreads();
#pragma unroll
      for (int i=0;i<16;++i){
        int m = g*16 + i;
        RhT[(size_t)(m0 + m)*2048 + k0 + c] = tl[c*65 + m];
      }
    } else {                                     // VhT[b][d][m] = V[b][m][d]
      const int pid = bid - 3072;
      const int m0 = (pid & 31)*64, b = pid >> 5;
#pragma unroll
      for (int i=0;i<16;++i){
        int m = g*16 + i;
        tl[m*65 + c] = (f16)V[((size_t)b*2048 + m0 + m)*64 + c];
      }
      __syncthreads();
#pragma unroll
      for (int i=0;i<16;++i){
        int d = g*16 + i;
        VhT[((size_t)b*64 + d)*2048 + m0 + c] = tl[c*65 + d];
      }
    }
    return;
  }

  // ---- QK tile: Ph[128x128] = relu(Q K^T)*0.125 ----
  f16* Qt = (f16*)shm;            // [128][72]
  f16* Kt = (f16*)(shm + 18432);  // [128][72]
  f16* Tt = (f16*)shm;            // [128][136] aliases after compute

  const int w = t>>6, l = t&63, lr = l&15, q = l>>4;
  const int m0 = (bid & 15)*128, n0 = ((bid>>4) & 15)*128, b = bid >> 8;
  const int wr = (w>>1)*64, wc = (w&1)*64;
  const float* Qb = Q  + ((size_t)b*2048 + n0)*64;
  const float* Kb = Km + ((size_t)b*2048 + m0)*64;

  const int sr = t>>3, sc = t&7;
#pragma unroll
  for (int j=0;j<4;++j){
    int row = sr + 32*j;
    const float* p  = Qb + (size_t)row*64 + sc*8;
    *(f16x8*)(Qt + row*72 + sc*8) = cvt_f16x8(*(const float4*)p, *(const float4*)(p+4));
    const float* pk = Kb + (size_t)row*64 + sc*8;
    *(f16x8*)(Kt + row*72 + sc*8) = cvt_f16x8(*(const float4*)pk, *(const float4*)(pk+4));
  }
  __syncthreads();

  f32x4 acc[4][4] = {};
#pragma unroll
  for (int kc=0;kc<2;++kc){
    f16x8 af[4], bf[4];
#pragma unroll
    for (int ti=0;ti<4;++ti) af[ti] = *(const f16x8*)(Qt + (wr+16*ti+lr)*72 + kc*32 + q*8);
#pragma unroll
    for (int tj=0;tj<4;++tj) bf[tj] = *(const f16x8*)(Kt + (wc+16*tj+lr)*72 + kc*32 + q*8);
#pragma unroll
    for (int ti=0;ti<4;++ti)
#pragma unroll
      for (int tj=0;tj<4;++tj)
        acc[ti][tj] = __builtin_amdgcn_mfma_f32_16x16x32_f16(af[ti], bf[tj], acc[ti][tj], 0,0,0);
  }
  __syncthreads();
#pragma unroll
  for (int ti=0;ti<4;++ti)
#pragma unroll
    for (int tj=0;tj<4;++tj)
#pragma unroll
      for (int r=0;r<4;++r)
        Tt[(wr+16*ti+4*q+r)*136 + wc+16*tj+lr] = (f16)(fmaxf(acc[ti][tj][r],0.f)*0.125f);
  __syncthreads();
  const int g16 = t&15, r0 = t>>4;
#pragma unroll
  for (int j=0;j<8;++j){
    int row = r0 + 16*j;
    *(f16x8*)(Ph + ((size_t)b*2048 + n0 + row)*2048 + m0 + g16*8) =
        *(const f16x8*)(Tt + row*136 + g16*8);
  }
}

// ---------------- kernel 2: split-j flash attention over scores ------------
// r7: OCCUPANCY. Evidence r0-r6: time invariant to global traffic (r5),
// worse with less LDS traffic (r6), invariant to pipeline depth (r1) ->
// latency-bound at the fixed 2 waves/SIMD imposed by acc[8][4]. Halve the
// per-wave accumulator: WG tile 64 rows x 256 j (wave tile 64x64, acc[4][4]
// = 64 regs, Ov 16), grid 2048 = 32 nb x 8 jq x 8 b. launch_bounds(256,3)
// -> 3 WGs/CU = 12 waves/CU. LDS 40KB (3x40 = 120 <= 160). Loop body,
// swizzle, staging identical to the proven r0/r5 structure.
// Decode: b=bid&7 (=XCD), jq=(bid>>3)&7, nb=bid>>6.
__launch_bounds__(256, 3)
__global__ void k_attn(const f16* __restrict__ Ph, const f16* __restrict__ RhT,
                       const f16* __restrict__ VhT, f16* __restrict__ Op,
                       float* __restrict__ mp, float* __restrict__ lp){
  __shared__ __align__(16) char smem[40960];
  f16*  Pbuf = (f16*)smem;                      // [2][64][32] = 8192
  f16*  Rbuf = (f16*)(smem + 8192);             // [2][256][32] = 32768
  f16*  El   = (f16*)smem;                      // [64][264] = 33792 (alias)
  float* stat_max = (float*)(smem + 33792);     // [64][4] = 1024
  float* stat_sum = (float*)(smem + 34816);     // [64][4] = 1024

  const int t = threadIdx.x, w = t>>6, l = t&63, lr = l&15, q = l>>4;
  const int bid = blockIdx.x;
  const int b = bid & 7, jq = (bid >> 3) & 7, nb = bid >> 6;
  const int n0 = nb*64, jg = jq*256;
  const int wc = w*64;

  const f16* Pblk = Ph  + ((size_t)b*2048 + n0)*2048;
  const f16* Vb   = VhT + (size_t)b*64*2048;

  // staging source pointers (pre-swizzled col-group, m173 pattern)
  const f16* srcP;                               // P: 4KB/buf = 1 load/thread
  {
    int row = t>>2, g = t&3;
    srcP = Pblk + (size_t)row*2048 + (g ^ ((row>>1)&3))*8;
  }
  const f16* srcR[4];                            // R: 16KB/buf = 4 loads/thread
#pragma unroll
  for (int i=0;i<4;++i){
    int slot = i*256 + t, row = slot>>2, g = slot&3;
    srcR[i] = RhT + (size_t)(jg + row)*2048 + (g ^ ((row>>1)&3))*8;
  }

  auto stage = [&](int kc){
    const int cb = kc & 1, k0 = kc*32;
    __builtin_amdgcn_global_load_lds(AS1C(srcP + k0),
                                     AS3(Pbuf + cb*2048 + w*512), 16, 0, 0);
#pragma unroll
    for (int i=0;i<4;++i)
      __builtin_amdgcn_global_load_lds(AS1C(srcR[i] + k0),
                                       AS3(Rbuf + cb*8192 + i*2048 + w*512), 16, 0, 0);
  };

  const int swz = (lr>>1)&3;                    // read-side XOR swizzle
  f32x4 acc[4][4] = {};
  f32x4 Oacc[2][2] = {};

  stage(0);
#pragma unroll 2
  for (int kc = 0; kc < 64; ++kc){
    __syncthreads();                            // chunk kc staged
    if (kc < 63) stage(kc+1);
    const int cb = kc & 1;
    const f16* Pb = Pbuf + cb*2048;
    const f16* Rb = Rbuf + cb*8192;
    f16x8 bf[4];
#pragma unroll
    for (int tj=0;tj<4;++tj)
      bf[tj] = *(const f16x8*)(Rb + (wc + 16*tj + lr)*32 + (q ^ swz)*8);
#pragma unroll
    for (int ti=0;ti<4;++ti){
      f16x8 af = *(const f16x8*)(Pb + (16*ti + lr)*32 + (q ^ swz)*8);
#pragma unroll
      for (int tj=0;tj<4;++tj)
        acc[ti][tj] = __builtin_amdgcn_mfma_f32_16x16x32_f16(af, bf[tj], acc[ti][tj], 0,0,0);
    }
  }
  __syncthreads();                              // staging dead; aliases usable

  // ---- softmax + E@V, single 64-row pass ----
  float pm[4][4];
#pragma unroll
  for (int ti=0;ti<4;++ti)
#pragma unroll
    for (int r=0;r<4;++r)
      pm[ti][r] = fmaxf(fmaxf(acc[ti][0][r], acc[ti][1][r]),
                        fmaxf(acc[ti][2][r], acc[ti][3][r]));
#pragma unroll
  for (int mm=1;mm<16;mm<<=1)
#pragma unroll
    for (int ti=0;ti<4;++ti)
#pragma unroll
      for (int r=0;r<4;++r)
        pm[ti][r] = fmaxf(pm[ti][r], __shfl_xor(pm[ti][r], mm));
  if (lr == 0)
#pragma unroll
    for (int ti=0;ti<4;++ti)
#pragma unroll
      for (int r=0;r<4;++r)
        stat_max[(16*ti + 4*q + r)*4 + w] = pm[ti][r];
  __syncthreads();                              // B1: per-wave maxima visible

  float Mn[4][4], ps[4][4];
#pragma unroll
  for (int ti=0;ti<4;++ti)
#pragma unroll
    for (int r=0;r<4;++r){
      int row = 16*ti + 4*q + r;
      float4 s4 = *(const float4*)&stat_max[row*4];
      Mn[ti][r] = fmaxf(fmaxf(s4.x,s4.y), fmaxf(s4.z,s4.w));
      ps[ti][r] = 0.f;
    }
#pragma unroll
  for (int ti=0;ti<4;++ti)
#pragma unroll
    for (int tj=0;tj<4;++tj)
#pragma unroll
      for (int r=0;r<4;++r){
        float e = __expf(acc[ti][tj][r] - Mn[ti][r]);
        ps[ti][r] += e;
        El[(16*ti + 4*q + r)*264 + wc + 16*tj + lr] = (f16)e;
      }
#pragma unroll
  for (int mm=1;mm<16;mm<<=1)
#pragma unroll
    for (int ti=0;ti<4;++ti)
#pragma unroll
      for (int r=0;r<4;++r)
        ps[ti][r] += __shfl_xor(ps[ti][r], mm);
  if (lr == 0)
#pragma unroll
    for (int ti=0;ti<4;++ti)
#pragma unroll
      for (int r=0;r<4;++r)
        stat_sum[(16*ti + 4*q + r)*4 + w] = ps[ti][r];
  __syncthreads();                              // B2: El + stat_sum visible

  if (w == 0 && lr == 0)                        // write per-row max/sum
#pragma unroll
    for (int ti=0;ti<4;++ti)
#pragma unroll
      for (int r=0;r<4;++r){
        int row = 16*ti + 4*q + r;
        float4 s4 = *(const float4*)&stat_sum[row*4];
        mp[bid*64 + row] = Mn[ti][r];
        lp[bid*64 + row] = s4.x + s4.y + s4.z + s4.w;
      }

  // ---- E @ V : O[64][64] += E[64][256] * V[256][64]
  const int erb = 32*(w&1), vcb = 32*(w>>1);
#pragma unroll
  for (int ks=0; ks<8; ++ks){
    f16x8 ae[2], bv[2];
#pragma unroll
    for (int a=0;a<2;++a)
      ae[a] = *(const f16x8*)(El + (erb + 16*a + lr)*264 + ks*32 + q*8);
#pragma unroll
    for (int bb=0;bb<2;++bb)
      bv[bb] = *(const f16x8*)(Vb + (size_t)(vcb + 16*bb + lr)*2048 + jg + ks*32 + q*8);
#pragma unroll
    for (int a=0;a<2;++a)
#pragma unroll
      for (int bb=0;bb<2;++bb)
        Oacc[a][bb] = __builtin_amdgcn_mfma_f32_16x16x32_f16(ae[a], bv[bb], Oacc[a][bb], 0,0,0);
  }

#pragma unroll
  for (int a=0;a<2;++a)
#pragma unroll
    for (int bb=0;bb<2;++bb)
#pragma unroll
      for (int r=0;r<4;++r){
        int row = 32*(w&1) + 16*a + 4*q + r;
        int col = 32*(w>>1) + 16*bb + lr;
        Op[((size_t)bid*64 + row)*64 + col] = (f16)Oacc[a][bb][r];
      }
}

// ---------------- kernel 3: combine the 8 j-slice partials -----------------
// Grid 512: rb = bid>>1 (0..255 = nb*8+b row-blocks of 64), qr = bid&1.
// Partial i for output block (nb,b) lives at k_attn bid = nb*64 + i*8 + b.
__global__ void k_comb(const f16* __restrict__ Op, const float* __restrict__ mp,
                       const float* __restrict__ lp, float* __restrict__ out){
  const int rb = blockIdx.x >> 1;               // 0..255 = nb*8 + b
  const int qr = blockIdx.x & 1;                // row half
  const int b = rb & 7, nb = rb >> 3;           // nb in [0,32)
  const int pb = nb*64 + b;                     // partial i at pb + i*8
  const int t = threadIdx.x;
  const int row = qr*32 + (t >> 3);             // 32 rows x 8 col-groups
  const int c0 = (t & 7)*8;

  float m_[8], a_[8];
  float M = -1e30f, den = 0.f;
#pragma unroll
  for (int i=0;i<8;++i){ m_[i] = mp[(pb + i*8)*64 + row]; M = fmaxf(M, m_[i]); }
#pragma unroll
  for (int i=0;i<8;++i){ a_[i] = __expf(m_[i] - M); den += a_[i]*lp[(pb + i*8)*64 + row]; }
  float inv = 1.0f / den;

  float o[8] = {};
#pragma unroll
  for (int i=0;i<8;++i){
    f16x8 v = *(const f16x8*)(Op + ((size_t)(pb + i*8)*64 + row)*64 + c0);
#pragma unroll
    for (int e=0;e<8;++e) o[e] += a_[i]*(float)v[e];
  }
  float4 o0, o1;
  o0.x=o[0]*inv; o0.y=o[1]*inv; o0.z=o[2]*inv; o0.w=o[3]*inv;
  o1.x=o[4]*inv; o1.y=o[5]*inv; o1.z=o[6]*inv; o1.w=o[7]*inv;
  float* dst = out + ((size_t)b*2048 + nb*64 + row)*64 + c0;
  *(float4*)dst = o0;
  *(float4*)(dst+4) = o1;
}

extern "C" void kernel_launch(void* const* d_in, const int* in_sizes, int n_in,
                              void* d_out, int out_size, void* d_ws, size_t ws_size,
                              hipStream_t stream){
  (void)in_sizes; (void)n_in; (void)out_size; (void)ws_size;
  const float* Q  = (const float*)d_in[0];
  const float* K  = (const float*)d_in[1];
  const float* V  = (const float*)d_in[2];
  const float* Dm = (const float*)d_in[3];
  float* out = (float*)d_out;
  char* ws = (char*)d_ws;
  f16* Ph  = (f16*)ws;                                   // 64 MB
  f16* RhT = (f16*)(ws + (size_t)64*1024*1024);          //  8 MB
  f16* VhT = (f16*)(ws + (size_t)72*1024*1024);          //  2 MB
  f16* Op  = (f16*)(ws + (size_t)74*1024*1024);          // 16 MB (2048*64*64 f16)
  float* mpp = (float*)(ws + (size_t)90*1024*1024);      // 512 KB
  float* lpp = mpp + 2048*64;                            // 512 KB

  k_qk   <<<dim3(3328), 256, 0, stream>>>(Q, K, V, Dm, Ph, RhT, VhT);
  k_attn <<<dim3(2048), 256, 0, stream>>>(Ph, RhT, VhT, Op, mpp, lpp);
  k_comb <<<dim3(512),  256, 0, stream>>>(Op, mpp, lpp, out);
}

// Round 8
// 283.122 us; speedup vs baseline: 1.0353x; 1.0353x over previous
//
#include <hip/hip_runtime.h>

// ScaledDotProductAttention: context = softmax(relu(Q K^T) @ R / 8) @ V
// B=8, N=2048, D=64. R = (1+e)/(1+exp(1-dist)), shared across batch.
//
// ws layout (~91.5 MB):
//   [0,   64MB)  Ph  : fp16 relu(QK^T)*0.125, [B][N][N]
//   [64MB,72MB)  RhT : fp16 R^T, [j][m]
//   [72MB,74MB)  VhT : fp16 V^T, [B][64][N]
//   [74MB,90MB)  Op  : fp16 partial O, [512 wg][256][64]
//   [90MB,...)   mp, lp : fp32 partial rowmax/rowsum, [512][256] each

typedef _Float16 f16;
typedef _Float16 f16x8 __attribute__((ext_vector_type(8)));
typedef float    f32x4 __attribute__((ext_vector_type(4)));

#define AS1C(p) ((const __attribute__((address_space(1))) void*)(p))
#define AS3(p)  ((__attribute__((address_space(3))) void*)(p))

__device__ __forceinline__ f16x8 cvt_f16x8(float4 a, float4 b){
  f16x8 v;
  v[0]=(f16)a.x; v[1]=(f16)a.y; v[2]=(f16)a.z; v[3]=(f16)a.w;
  v[4]=(f16)b.x; v[5]=(f16)b.y; v[6]=(f16)b.z; v[7]=(f16)b.w;
  return v;
}

// ---------------- kernel 1: fused prep + QK^T --------------------------------
__launch_bounds__(256, 2)
__global__ void k_qk(const float* __restrict__ Q, const float* __restrict__ Km,
                     const float* __restrict__ V, const float* __restrict__ Dm,
                     f16* __restrict__ Ph, f16* __restrict__ RhT,
                     f16* __restrict__ VhT){
  __shared__ __align__(16) char shm[36864];
  const int bid = blockIdx.x;
  const int t = threadIdx.x;

  if (bid >= 2048){
    f16* tl = (f16*)shm;                         // [64][65]
    const int c = t & 63, g = t >> 6;
    if (bid < 3072){                             // RhT[j][m] = rescale(D[m][j])
      const int pid = bid - 2048;
      const int k0 = (pid & 31)*64, m0 = (pid >> 5)*64;
#pragma unroll
      for (int i=0;i<16;++i){
        int k = g*16 + i;
        float d = Dm[(size_t)(k0 + k)*2048 + m0 + c];
        tl[k*65 + c] = (f16)(3.7182818284590452f / (1.0f + __expf(1.0f - d)));
      }
      __syncthreads();
#pragma unroll
      for (int i=0;i<16;++i){
        int m = g*16 + i;
        RhT[(size_t)(m0 + m)*2048 + k0 + c] = tl[c*65 + m];
      }
    } else {                                     // VhT[b][d][m] = V[b][m][d]
      const int pid = bid - 3072;
      const int m0 = (pid & 31)*64, b = pid >> 5;
#pragma unroll
      for (int i=0;i<16;++i){
        int m = g*16 + i;
        tl[m*65 + c] = (f16)V[((size_t)b*2048 + m0 + m)*64 + c];
      }
      __syncthreads();
#pragma unroll
      for (int i=0;i<16;++i){
        int d = g*16 + i;
        VhT[((size_t)b*64 + d)*2048 + m0 + c] = tl[c*65 + d];
      }
    }
    return;
  }

  // ---- QK tile: Ph[128x128] = relu(Q K^T)*0.125 ----
  f16* Qt = (f16*)shm;            // [128][72]
  f16* Kt = (f16*)(shm + 18432);  // [128][72]
  f16* Tt = (f16*)shm;            // [128][136] aliases after compute

  const int w = t>>6, l = t&63, lr = l&15, q = l>>4;
  const int m0 = (bid & 15)*128, n0 = ((bid>>4) & 15)*128, b = bid >> 8;
  const int wr = (w>>1)*64, wc = (w&1)*64;
  const float* Qb = Q  + ((size_t)b*2048 + n0)*64;
  const float* Kb = Km + ((size_t)b*2048 + m0)*64;

  const int sr = t>>3, sc = t&7;
#pragma unroll
  for (int j=0;j<4;++j){
    int row = sr + 32*j;
    const float* p  = Qb + (size_t)row*64 + sc*8;
    *(f16x8*)(Qt + row*72 + sc*8) = cvt_f16x8(*(const float4*)p, *(const float4*)(p+4));
    const float* pk = Kb + (size_t)row*64 + sc*8;
    *(f16x8*)(Kt + row*72 + sc*8) = cvt_f16x8(*(const float4*)pk, *(const float4*)(pk+4));
  }
  __syncthreads();

  f32x4 acc[4][4] = {};
#pragma unroll
  for (int kc=0;kc<2;++kc){
    f16x8 af[4], bf[4];
#pragma unroll
    for (int ti=0;ti<4;++ti) af[ti] = *(const f16x8*)(Qt + (wr+16*ti+lr)*72 + kc*32 + q*8);
#pragma unroll
    for (int tj=0;tj<4;++tj) bf[tj] = *(const f16x8*)(Kt + (wc+16*tj+lr)*72 + kc*32 + q*8);
#pragma unroll
    for (int ti=0;ti<4;++ti)
#pragma unroll
      for (int tj=0;tj<4;++tj)
        acc[ti][tj] = __builtin_amdgcn_mfma_f32_16x16x32_f16(af[ti], bf[tj], acc[ti][tj], 0,0,0);
  }
  __syncthreads();
#pragma unroll
  for (int ti=0;ti<4;++ti)
#pragma unroll
    for (int tj=0;tj<4;++tj)
#pragma unroll
      for (int r=0;r<4;++r)
        Tt[(wr+16*ti+4*q+r)*136 + wc+16*tj+lr] = (f16)(fmaxf(acc[ti][tj][r],0.f)*0.125f);
  __syncthreads();
  const int g16 = t&15, r0 = t>>4;
#pragma unroll
  for (int j=0;j<8;++j){
    int row = r0 + 16*j;
    *(f16x8*)(Ph + ((size_t)b*2048 + n0 + row)*2048 + m0 + g16*8) =
        *(const f16x8*)(Tt + row*136 + g16*8);
  }
}

// ---------------- kernel 2: 256x256 tile, 8-wave, 4-fine-phase K-loop -------
// Grid 512 = 8 nb x 8 jq x 8 b; b = bid&7 = XCD (r5 L2 remap kept).
// Per WG: 512 thr / 8 waves; wave (wr=w>>2, wc2=w&3) owns rows wr*128+...128,
// cols wc2*64+...64 of S[256][256]. K(m)-loop: 32 tiles of BK=64, split in
// kc-halves h0/h1 (regions [256][32] f16 = 16KB each; A,B x dbuf = 128KB).
// Per K-tile: 4 phases x {half-stage(2 gload_lds) | ds_reads | lgkmcnt(0)
// +sched_barrier | setprio(1) 16 MFMA setprio(0)}; counted vmcnt(4) + barrier
// ONLY at p0/p2 (T3+T4). vmcnt ledger (FIFO A_h0,B_h0,A_h1,B_h1 per tile,
// stage kt+1 spread over kt's phases): at p0 outstanding=8, keep 4 newest ->
// kt's h0 landed; at p2 outstanding=8, keep 4 newest -> kt's h1 landed.
// Dbuf overwrite safety: stage(kt+1) writes parity (kt+1)&1 holding kt-1's
// data; every wave passed kt-p0's barrier only after lgkm-completing ALL
// kt-1 reads. r3's bug was __launch_bounds__(512,2) => VGPR cap 128 =>
// ~60-reg spill (WRITE_SIZE 120MB); (512,1) => cap 256, acc(128)+frags fit.
__launch_bounds__(512, 1)
__global__ void k_attn(const f16* __restrict__ Ph, const f16* __restrict__ RhT,
                       const f16* __restrict__ VhT, f16* __restrict__ Op,
                       float* __restrict__ mp, float* __restrict__ lp){
  __shared__ __align__(16) char smem[131072];
  f16* As = (f16*)smem;                      // [2 par][2 h][256][32] = 64KB
  f16* Bs = (f16*)(smem + 65536);            // [2 par][2 h][256][32] = 64KB
  f16* El = (f16*)smem;                      // [128][264] = 67584 (alias)
  float* stat_max = (float*)(smem + 67584);  // [128][4] (alias)
  float* stat_sum = (float*)(smem + 69632);  // [128][4] (alias)

  const int t = threadIdx.x, w = t>>6, l = t&63, lr = l&15, q = l>>4;
  const int wr = w>>2, wc2 = w&3;
  const int bid = blockIdx.x;
  const int b = bid & 7, jq = (bid >> 3) & 7, nb = bid >> 6;
  const int n0 = nb*256, jg = jq*256;

  const f16* Pblk = Ph  + ((size_t)b*2048 + n0)*2048;
  const f16* Vb   = VhT + (size_t)b*64*2048;

  // staging sources (pre-swizzled col-group, m173 pattern); h = kc-half
  const f16* srcA[2][2];
  const f16* srcB[2][2];
#pragma unroll
  for (int h=0;h<2;++h)
#pragma unroll
    for (int i=0;i<2;++i){
      int slot = i*512 + t, row = slot>>2, g = slot&3;
      srcA[h][i] = Pblk + (size_t)row*2048 + h*32 + (g ^ ((row>>1)&3))*8;
      srcB[h][i] = RhT + (size_t)(jg + row)*2048 + h*32 + (g ^ ((row>>1)&3))*8;
    }

  auto stageA = [&](int kt, int h){
    const int par = kt & 1, k0 = kt*64;
#pragma unroll
    for (int i=0;i<2;++i)
      __builtin_amdgcn_global_load_lds(AS1C(srcA[h][i] + k0),
          AS3(As + par*16384 + h*8192 + (i*512 + t)*8), 16, 0, 0);
  };
  auto stageB = [&](int kt, int h){
    const int par = kt & 1, k0 = kt*64;
#pragma unroll
    for (int i=0;i<2;++i)
      __builtin_amdgcn_global_load_lds(AS1C(srcB[h][i] + k0),
          AS3(Bs + par*16384 + h*8192 + (i*512 + t)*8), 16, 0, 0);
  };

  const int swz = (lr>>1)&3;                 // read-side XOR swizzle
  f32x4 acc[8][4] = {};

  // prologue: FIFO order A_h0, B_h0, A_h1, B_h1 (8 loads)
  stageA(0,0); stageB(0,0); stageA(0,1); stageB(0,1);

  for (int kt = 0; kt < 32; ++kt){
    const f16* Ab = As + (kt&1)*16384;
    const f16* Bb = Bs + (kt&1)*16384;
    f16x8 bf[4], af[4];

    // ---- p0: h0, rows rh0 ----
    asm volatile("s_waitcnt vmcnt(4)" ::: "memory");  // kt's A_h0,B_h0 landed
    __builtin_amdgcn_s_barrier();
    __builtin_amdgcn_sched_barrier(0);
    if (kt < 31) stageA(kt+1, 0);
#pragma unroll
    for (int tj=0;tj<4;++tj)
      bf[tj] = *(const f16x8*)(Bb + (wc2*64 + 16*tj + lr)*32 + (q^swz)*8);
#pragma unroll
    for (int ti=0;ti<4;++ti)
      af[ti] = *(const f16x8*)(Ab + (wr*128 + 16*ti + lr)*32 + (q^swz)*8);
    asm volatile("s_waitcnt lgkmcnt(0)" ::: "memory");
    __builtin_amdgcn_sched_barrier(0);
    __builtin_amdgcn_s_setprio(1);
#pragma unroll
    for (int ti=0;ti<4;++ti)
#pragma unroll
      for (int tj=0;tj<4;++tj)
        acc[ti][tj] = __builtin_amdgcn_mfma_f32_16x16x32_f16(af[ti], bf[tj], acc[ti][tj], 0,0,0);
    __builtin_amdgcn_s_setprio(0);

    // ---- p1: h0, rows rh1 (bf reused) ----
    if (kt < 31) stageB(kt+1, 0);
#pragma unroll
    for (int ti=0;ti<4;++ti)
      af[ti] = *(const f16x8*)(Ab + (wr*128 + 64 + 16*ti + lr)*32 + (q^swz)*8);
    asm volatile("s_waitcnt lgkmcnt(0)" ::: "memory");
    __builtin_amdgcn_sched_barrier(0);
    __builtin_amdgcn_s_setprio(1);
#pragma unroll
    for (int ti=0;ti<4;++ti)
#pragma unroll
      for (int tj=0;tj<4;++tj)
        acc[4+ti][tj] = __builtin_amdgcn_mfma_f32_16x16x32_f16(af[ti], bf[tj], acc[4+ti][tj], 0,0,0);
    __builtin_amdgcn_s_setprio(0);

    // ---- p2: h1, rows rh0 ----
    if (kt < 31) { asm volatile("s_waitcnt vmcnt(4)" ::: "memory"); }
    else         { asm volatile("s_waitcnt vmcnt(0)" ::: "memory"); }
    __builtin_amdgcn_s_barrier();
    __builtin_amdgcn_sched_barrier(0);
    if (kt < 31) stageA(kt+1, 1);
#pragma unroll
    for (int tj=0;tj<4;++tj)
      bf[tj] = *(const f16x8*)(Bb + 8192 + (wc2*64 + 16*tj + lr)*32 + (q^swz)*8);
#pragma unroll
    for (int ti=0;ti<4;++ti)
      af[ti] = *(const f16x8*)(Ab + 8192 + (wr*128 + 16*ti + lr)*32 + (q^swz)*8);
    asm volatile("s_waitcnt lgkmcnt(0)" ::: "memory");
    __builtin_amdgcn_sched_barrier(0);
    __builtin_amdgcn_s_setprio(1);
#pragma unroll
    for (int ti=0;ti<4;++ti)
#pragma unroll
      for (int tj=0;tj<4;++tj)
        acc[ti][tj] = __builtin_amdgcn_mfma_f32_16x16x32_f16(af[ti], bf[tj], acc[ti][tj], 0,0,0);
    __builtin_amdgcn_s_setprio(0);

    // ---- p3: h1, rows rh1 (bf reused) ----
    if (kt < 31) stageB(kt+1, 1);
#pragma unroll
    for (int ti=0;ti<4;++ti)
      af[ti] = *(const f16x8*)(Ab + 8192 + (wr*128 + 64 + 16*ti + lr)*32 + (q^swz)*8);
    asm volatile("s_waitcnt lgkmcnt(0)" ::: "memory");
    __builtin_amdgcn_sched_barrier(0);
    __builtin_amdgcn_s_setprio(1);
#pragma unroll
    for (int ti=0;ti<4;++ti)
#pragma unroll
      for (int tj=0;tj<4;++tj)
        acc[4+ti][tj] = __builtin_amdgcn_mfma_f32_16x16x32_f16(af[ti], bf[tj], acc[4+ti][tj], 0,0,0);
    __builtin_amdgcn_s_setprio(0);
  }
  __syncthreads();                           // staging dead; aliases usable

  // ---- softmax + E@V in two 128-row passes (r3-verified epilogue) ----
#pragma unroll
  for (int p=0;p<2;++p){
    float Mn[8][4];
    if (wr == p){
      float pm[8][4];
#pragma unroll
      for (int ti=0;ti<8;++ti)
#pragma unroll
        for (int r=0;r<4;++r)
          pm[ti][r] = fmaxf(fmaxf(acc[ti][0][r], acc[ti][1][r]),
                            fmaxf(acc[ti][2][r], acc[ti][3][r]));
#pragma unroll
      for (int mm=1;mm<16;mm<<=1)
#pragma unroll
        for (int ti=0;ti<8;++ti)
#pragma unroll
          for (int r=0;r<4;++r)
            pm[ti][r] = fmaxf(pm[ti][r], __shfl_xor(pm[ti][r], mm));
      if (lr == 0)
#pragma unroll
        for (int ti=0;ti<8;++ti)
#pragma unroll
          for (int r=0;r<4;++r)
            stat_max[(16*ti + 4*q + r)*4 + wc2] = pm[ti][r];
    }
    __syncthreads();                         // B1: per-wave maxima visible

    if (wr == p){
      float ps[8][4];
#pragma unroll
      for (int ti=0;ti<8;++ti)
#pragma unroll
        for (int r=0;r<4;++r){
          int row = 16*ti + 4*q + r;
          float4 s4 = *(const float4*)&stat_max[row*4];
          Mn[ti][r] = fmaxf(fmaxf(s4.x,s4.y), fmaxf(s4.z,s4.w));
          ps[ti][r] = 0.f;
        }
#pragma unroll
      for (int ti=0;ti<8;++ti)
#pragma unroll
        for (int tj=0;tj<4;++tj)
#pragma unroll
          for (int r=0;r<4;++r){
            float e = __expf(acc[ti][tj][r] - Mn[ti][r]);
            ps[ti][r] += e;
            El[(16*ti + 4*q + r)*264 + wc2*64 + 16*tj + lr] = (f16)e;
          }
#pragma unroll
      for (int mm=1;mm<16;mm<<=1)
#pragma unroll
        for (int ti=0;ti<8;++ti)
#pragma unroll
          for (int r=0;r<4;++r)
            ps[ti][r] += __shfl_xor(ps[ti][r], mm);
      if (lr == 0)
#pragma unroll
        for (int ti=0;ti<8;++ti)
#pragma unroll
          for (int r=0;r<4;++r)
            stat_sum[(16*ti + 4*q + r)*4 + wc2] = ps[ti][r];
    }
    __syncthreads();                         // B2: El + stat_sum visible

    if (wr == p && wc2 == 0 && lr == 0)
#pragma unroll
      for (int ti=0;ti<8;++ti)
#pragma unroll
        for (int r=0;r<4;++r){
          int row = 16*ti + 4*q + r;
          float4 s4 = *(const float4*)&stat_sum[row*4];
          mp[bid*256 + p*128 + row] = Mn[ti][r];
          lp[bid*256 + p*128 + row] = s4.x + s4.y + s4.z + s4.w;
        }

    // ---- E @ V : all 8 waves; wave w owns rows [w*16, +16) of this pass
    {
      const int er0 = w*16;
      f32x4 Ov[4] = {};
#pragma unroll
      for (int ks=0; ks<8; ++ks){
        f16x8 ae = *(const f16x8*)(El + (er0 + lr)*264 + ks*32 + q*8);
        f16x8 bv[4];
#pragma unroll
        for (int tj2=0;tj2<4;++tj2)
          bv[tj2] = *(const f16x8*)(Vb + (size_t)(16*tj2 + lr)*2048 + jg + ks*32 + q*8);
#pragma unroll
        for (int tj2=0;tj2<4;++tj2)
          Ov[tj2] = __builtin_amdgcn_mfma_f32_16x16x32_f16(ae, bv[tj2], Ov[tj2], 0,0,0);
      }
#pragma unroll
      for (int tj2=0;tj2<4;++tj2)
#pragma unroll
        for (int r=0;r<4;++r)
          Op[((size_t)bid*256 + p*128 + er0 + 4*q + r)*64 + 16*tj2 + lr] = (f16)Ov[tj2][r];
    }
    __syncthreads();                         // B3: El reads done before pass 1
  }
}

// ---------------- kernel 3: combine the 8 j-slice partials -----------------
// Grid 512: rb = bid>>3 (0..63 = nb*8+b), qr = bid&7 (32-row chunk of 256).
// Partial jq for (nb,b) lives at k_attn bid = nb*64 + jq*8 + b.
__global__ void k_comb(const f16* __restrict__ Op, const float* __restrict__ mp,
                       const float* __restrict__ lp, float* __restrict__ out){
  const int rb = blockIdx.x >> 3;
  const int qr = blockIdx.x & 7;
  const int b = rb & 7, nb = rb >> 3;
  const int pb = nb*64 + b;                  // partial i at pb + i*8
  const int t = threadIdx.x;
  const int row = qr*32 + (t >> 3);          // 0..255
  const int c0 = (t & 7)*8;

  float m_[8], a_[8];
  float M = -1e30f, den = 0.f;
#pragma unroll
  for (int i=0;i<8;++i){ m_[i] = mp[(pb + i*8)*256 + row]; M = fmaxf(M, m_[i]); }
#pragma unroll
  for (int i=0;i<8;++i){ a_[i] = __expf(m_[i] - M); den += a_[i]*lp[(pb + i*8)*256 + row]; }
  float inv = 1.0f / den;

  float o[8] = {};
#pragma unroll
  for (int i=0;i<8;++i){
    f16x8 v = *(const f16x8*)(Op + ((size_t)(pb + i*8)*256 + row)*64 + c0);
#pragma unroll
    for (int e=0;e<8;++e) o[e] += a_[i]*(float)v[e];
  }
  float4 o0, o1;
  o0.x=o[0]*inv; o0.y=o[1]*inv; o0.z=o[2]*inv; o0.w=o[3]*inv;
  o1.x=o[4]*inv; o1.y=o[5]*inv; o1.z=o[6]*inv; o1.w=o[7]*inv;
  float* dst = out + ((size_t)b*2048 + nb*256 + row)*64 + c0;
  *(float4*)dst = o0;
  *(float4*)(dst+4) = o1;
}

extern "C" void kernel_launch(void* const* d_in, const int* in_sizes, int n_in,
                              void* d_out, int out_size, void* d_ws, size_t ws_size,
                              hipStream_t stream){
  (void)in_sizes; (void)n_in; (void)out_size; (void)ws_size;
  const float* Q  = (const float*)d_in[0];
  const float* K  = (const float*)d_in[1];
  const float* V  = (const float*)d_in[2];
  const float* Dm = (const float*)d_in[3];
  float* out = (float*)d_out;
  char* ws = (char*)d_ws;
  f16* Ph  = (f16*)ws;                                   // 64 MB
  f16* RhT = (f16*)(ws + (size_t)64*1024*1024);          //  8 MB
  f16* VhT = (f16*)(ws + (size_t)72*1024*1024);          //  2 MB
  f16* Op  = (f16*)(ws + (size_t)74*1024*1024);          // 16 MB (512*256*64 f16)
  float* mpp = (float*)(ws + (size_t)90*1024*1024);      // 512 KB
  float* lpp = mpp + 512*256;                            // 512 KB

  k_qk   <<<dim3(3328), 256, 0, stream>>>(Q, K, V, Dm, Ph, RhT, VhT);
  k_attn <<<dim3(512),  512, 0, stream>>>(Ph, RhT, VhT, Op, mpp, lpp);
  k_comb <<<dim3(512),  256, 0, stream>>>(Op, mpp, lpp, out);
}

// Round 9
// 236.383 us; speedup vs baseline: 1.2400x; 1.1977x over previous
//
#include <hip/hip_runtime.h>

// ScaledDotProductAttention: context = softmax(relu(Q K^T) @ R / 8) @ V
// B=8, N=2048, D=64. R = (1+e)/(1+exp(1-dist)), shared across batch.
//
// ws layout (needs ~91.5 MB):
//   [0,   64MB)  Ph  : fp16 relu(QK^T)*0.125, [B][N][N]
//   [64MB,72MB)  RhT : fp16 R^T, [j][m]
//   [72MB,74MB)  VhT : fp16 V^T, [B][64][N]
//   [74MB,90MB)  Op  : fp16 partial O, [1024 wg][128][64]
//   [90MB,...)   mp, lp : fp32 partial rowmax/rowsum, [1024][128] each

typedef _Float16 f16;
typedef _Float16 f16x8 __attribute__((ext_vector_type(8)));
typedef float    f32x4 __attribute__((ext_vector_type(4)));

#define AS1C(p) ((const __attribute__((address_space(1))) void*)(p))
#define AS3(p)  ((__attribute__((address_space(3))) void*)(p))

__device__ __forceinline__ f16x8 cvt_f16x8(float4 a, float4 b){
  f16x8 v;
  v[0]=(f16)a.x; v[1]=(f16)a.y; v[2]=(f16)a.z; v[3]=(f16)a.w;
  v[4]=(f16)b.x; v[5]=(f16)b.y; v[6]=(f16)b.z; v[7]=(f16)b.w;
  return v;
}

// ---------------- kernel 1: fused prep + QK^T --------------------------------
// Flat grid 3328: [0,2048) QK tiles; [2048,3072) rescale-transpose tiles;
// [3072,3328) V-transpose tiles. One launch instead of three.
__launch_bounds__(256, 2)
__global__ void k_qk(const float* __restrict__ Q, const float* __restrict__ Km,
                     const float* __restrict__ V, const float* __restrict__ Dm,
                     f16* __restrict__ Ph, f16* __restrict__ RhT,
                     f16* __restrict__ VhT){
  __shared__ __align__(16) char shm[36864];
  const int bid = blockIdx.x;
  const int t = threadIdx.x;

  if (bid >= 2048){
    f16* tl = (f16*)shm;                         // [64][65]
    const int c = t & 63, g = t >> 6;
    if (bid < 3072){                             // RhT[j][m] = rescale(D[m][j])
      const int pid = bid - 2048;
      const int k0 = (pid & 31)*64, m0 = (pid >> 5)*64;
#pragma unroll
      for (int i=0;i<16;++i){
        int k = g*16 + i;
        float d = Dm[(size_t)(k0 + k)*2048 + m0 + c];
        tl[k*65 + c] = (f16)(3.7182818284590452f / (1.0f + __expf(1.0f - d)));
      }
      __syncthreads();
#pragma unroll
      for (int i=0;i<16;++i){
        int m = g*16 + i;
        RhT[(size_t)(m0 + m)*2048 + k0 + c] = tl[c*65 + m];
      }
    } else {                                     // VhT[b][d][m] = V[b][m][d]
      const int pid = bid - 3072;
      const int m0 = (pid & 31)*64, b = pid >> 5;
#pragma unroll
      for (int i=0;i<16;++i){
        int m = g*16 + i;
        tl[m*65 + c] = (f16)V[((size_t)b*2048 + m0 + m)*64 + c];
      }
      __syncthreads();
#pragma unroll
      for (int i=0;i<16;++i){
        int d = g*16 + i;
        VhT[((size_t)b*64 + d)*2048 + m0 + c] = tl[c*65 + d];
      }
    }
    return;
  }

  // ---- QK tile: Ph[128x128] = relu(Q K^T)*0.125 ----
  f16* Qt = (f16*)shm;            // [128][72]
  f16* Kt = (f16*)(shm + 18432);  // [128][72]
  f16* Tt = (f16*)shm;            // [128][136] aliases after compute

  const int w = t>>6, l = t&63, lr = l&15, q = l>>4;
  const int m0 = (bid & 15)*128, n0 = ((bid>>4) & 15)*128, b = bid >> 8;
  const int wr = (w>>1)*64, wc = (w&1)*64;
  const float* Qb = Q  + ((size_t)b*2048 + n0)*64;
  const float* Kb = Km + ((size_t)b*2048 + m0)*64;

  const int sr = t>>3, sc = t&7;
#pragma unroll
  for (int j=0;j<4;++j){
    int row = sr + 32*j;
    const float* p  = Qb + (size_t)row*64 + sc*8;
    *(f16x8*)(Qt + row*72 + sc*8) = cvt_f16x8(*(const float4*)p, *(const float4*)(p+4));
    const float* pk = Kb + (size_t)row*64 + sc*8;
    *(f16x8*)(Kt + row*72 + sc*8) = cvt_f16x8(*(const float4*)pk, *(const float4*)(pk+4));
  }
  __syncthreads();

  f32x4 acc[4][4] = {};
#pragma unroll
  for (int kc=0;kc<2;++kc){
    f16x8 af[4], bf[4];
#pragma unroll
    for (int ti=0;ti<4;++ti) af[ti] = *(const f16x8*)(Qt + (wr+16*ti+lr)*72 + kc*32 + q*8);
#pragma unroll
    for (int tj=0;tj<4;++tj) bf[tj] = *(const f16x8*)(Kt + (wc+16*tj+lr)*72 + kc*32 + q*8);
#pragma unroll
    for (int ti=0;ti<4;++ti)
#pragma unroll
      for (int tj=0;tj<4;++tj)
        acc[ti][tj] = __builtin_amdgcn_mfma_f32_16x16x32_f16(af[ti], bf[tj], acc[ti][tj], 0,0,0);
  }
  __syncthreads();
#pragma unroll
  for (int ti=0;ti<4;++ti)
#pragma unroll
    for (int tj=0;tj<4;++tj)
#pragma unroll
      for (int r=0;r<4;++r)
        Tt[(wr+16*ti+4*q+r)*136 + wc+16*tj+lr] = (f16)(fmaxf(acc[ti][tj][r],0.f)*0.125f);
  __syncthreads();
  const int g16 = t&15, r0 = t>>4;
#pragma unroll
  for (int j=0;j<8;++j){
    int row = r0 + 16*j;
    *(f16x8*)(Ph + ((size_t)b*2048 + n0 + row)*2048 + m0 + g16*8) =
        *(const f16x8*)(Tt + row*136 + g16*8);
  }
}

// ---------------- kernel 2: split-j flash attention over scores ------------
// r9 = r5 (best measured) + two bounded deltas:
//  (1) s_setprio(1/0) around the MFMA cluster: with 2 co-resident WGs per CU
//      at independent phases, the MFMA-phase wave preempts the staging wave
//      (m191 attention mechanism, +4-7%; never isolated before — r1 bundled
//      it with a regressing pipeline rewrite).
//  (2) Oacc decl/init sunk below the S-loop: removes a 32-reg live range
//      spanning the loop (reg headroom; semantics identical).
// Decode: b=bid&7 (=XCD), jq=(bid>>3)&7, nb=bid>>6 (r5 L2 remap: FETCH
// 273->100MB). Structure: 1 syncthreads/chunk, dbuf global_load_lds (proven
// fastest across r0-r8; every structural variant regressed).
__launch_bounds__(256, 2)
__global__ void k_attn(const f16* __restrict__ Ph, const f16* __restrict__ RhT,
                       const f16* __restrict__ VhT, f16* __restrict__ Op,
                       float* __restrict__ mp, float* __restrict__ lp){
  __shared__ __align__(16) char smem[49152];
  f16*  Pbuf = (f16*)smem;                      // [2][128][32] = 16384
  f16*  Rbuf = (f16*)(smem + 16384);            // [2][256][32] = 32768
  f16*  El   = (f16*)smem;                      // [64][264] = 33792 (alias)
  float* stat_max = (float*)(smem + 33792);     // [64][4] = 1024 (alias)
  float* stat_sum = (float*)(smem + 34816);     // [64][4] = 1024 (alias)

  const int t = threadIdx.x, w = t>>6, l = t&63, lr = l&15, q = l>>4;
  const int bid = blockIdx.x;
  const int b = bid & 7, jq = (bid >> 3) & 7, nb = bid >> 6;
  const int n0 = nb*128, jg = jq*256;
  const int wc = w*64;

  const f16* Pblk = Ph  + ((size_t)b*2048 + n0)*2048;
  const f16* Vb   = VhT + (size_t)b*64*2048;

  // hoisted staging source pointers (advance by kc*32 halves each chunk)
  const f16* srcP[2];
  const f16* srcR[4];
#pragma unroll
  for (int i=0;i<2;++i){
    int slot = i*256 + t, row = slot>>2, g = slot&3;
    srcP[i] = Pblk + (size_t)row*2048 + (g ^ ((row>>1)&3))*8;
  }
#pragma unroll
  for (int i=0;i<4;++i){
    int slot = i*256 + t, row = slot>>2, g = slot&3;
    srcR[i] = RhT + (size_t)(jg + row)*2048 + (g ^ ((row>>1)&3))*8;
  }

  auto stage = [&](int kc){
    const int cb = kc & 1, k0 = kc*32;
#pragma unroll
    for (int i=0;i<2;++i)
      __builtin_amdgcn_global_load_lds(AS1C(srcP[i] + k0),
                                       AS3(Pbuf + cb*4096 + i*2048 + w*512), 16, 0, 0);
#pragma unroll
    for (int i=0;i<4;++i)
      __builtin_amdgcn_global_load_lds(AS1C(srcR[i] + k0),
                                       AS3(Rbuf + cb*8192 + i*2048 + w*512), 16, 0, 0);
  };

  const int swz = (lr>>1)&3;                    // read-side XOR swizzle
  f32x4 acc[8][4] = {};

  stage(0);
#pragma unroll 2
  for (int kc = 0; kc < 64; ++kc){
    __syncthreads();                            // chunk kc staged
    if (kc < 63) stage(kc+1);
    const int cb = kc & 1;
    const f16* Pb = Pbuf + cb*4096;
    const f16* Rb = Rbuf + cb*8192;
    f16x8 bf[4];
#pragma unroll
    for (int tj=0;tj<4;++tj)
      bf[tj] = *(const f16x8*)(Rb + (wc + 16*tj + lr)*32 + (q ^ swz)*8);
    __builtin_amdgcn_s_setprio(1);
#pragma unroll
    for (int ti=0;ti<8;++ti){
      f16x8 af = *(const f16x8*)(Pb + (16*ti + lr)*32 + (q ^ swz)*8);
#pragma unroll
      for (int tj=0;tj<4;++tj)
        acc[ti][tj] = __builtin_amdgcn_mfma_f32_16x16x32_f16(af, bf[tj], acc[ti][tj], 0,0,0);
    }
    __builtin_amdgcn_s_setprio(0);
  }
  __syncthreads();                              // staging dead; aliases usable

  // ---- softmax + E@V in two 64-row passes (single epilogue, no running m/l)
  f32x4 Oacc[2][2][2] = {};                     // sunk below S-loop (reg headroom)
#pragma unroll
  for (int p=0;p<2;++p){
    float pm[4][4];
#pragma unroll
    for (int ti=0;ti<4;++ti)
#pragma unroll
      for (int r=0;r<4;++r)
        pm[ti][r] = fmaxf(fmaxf(acc[4*p+ti][0][r], acc[4*p+ti][1][r]),
                          fmaxf(acc[4*p+ti][2][r], acc[4*p+ti][3][r]));
#pragma unroll
    for (int mm=1;mm<16;mm<<=1)
#pragma unroll
      for (int ti=0;ti<4;++ti)
#pragma unroll
        for (int r=0;r<4;++r)
          pm[ti][r] = fmaxf(pm[ti][r], __shfl_xor(pm[ti][r], mm));
    if (lr == 0)
#pragma unroll
      for (int ti=0;ti<4;++ti)
#pragma unroll
        for (int r=0;r<4;++r)
          stat_max[(16*ti + 4*q + r)*4 + w] = pm[ti][r];
    __syncthreads();                            // B1: per-wave maxima visible

    float Mn[4][4], ps[4][4];
#pragma unroll
    for (int ti=0;ti<4;++ti)
#pragma unroll
      for (int r=0;r<4;++r){
        int row = 16*ti + 4*q + r;
        float4 s4 = *(const float4*)&stat_max[row*4];
        Mn[ti][r] = fmaxf(fmaxf(s4.x,s4.y), fmaxf(s4.z,s4.w));
        ps[ti][r] = 0.f;
      }
#pragma unroll
    for (int ti=0;ti<4;++ti)
#pragma unroll
      for (int tj=0;tj<4;++tj)
#pragma unroll
        for (int r=0;r<4;++r){
          float e = __expf(acc[4*p+ti][tj][r] - Mn[ti][r]);
          ps[ti][r] += e;
          El[(16*ti + 4*q + r)*264 + wc + 16*tj + lr] = (f16)e;
        }
#pragma unroll
    for (int mm=1;mm<16;mm<<=1)
#pragma unroll
      for (int ti=0;ti<4;++ti)
#pragma unroll
        for (int r=0;r<4;++r)
          ps[ti][r] += __shfl_xor(ps[ti][r], mm);
    if (lr == 0)
#pragma unroll
      for (int ti=0;ti<4;++ti)
#pragma unroll
        for (int r=0;r<4;++r)
          stat_sum[(16*ti + 4*q + r)*4 + w] = ps[ti][r];
    __syncthreads();                            // B2: El + stat_sum visible

    if (w == 0 && lr == 0)                      // write per-row max/sum
#pragma unroll
      for (int ti=0;ti<4;++ti)
#pragma unroll
        for (int r=0;r<4;++r){
          int row = 16*ti + 4*q + r;
          float4 s4 = *(const float4*)&stat_sum[row*4];
          mp[bid*128 + 64*p + row] = Mn[ti][r];
          lp[bid*128 + 64*p + row] = s4.x + s4.y + s4.z + s4.w;
        }

    // ---- E @ V : O[pass rows][cols] += E[64][256] * V[256][64]
    const int erb = 32*(w&1), vcb = 32*(w>>1);
#pragma unroll
    for (int ks=0; ks<8; ++ks){
      f16x8 ae[2], bv[2];
#pragma unroll
      for (int a=0;a<2;++a)
        ae[a] = *(const f16x8*)(El + (erb + 16*a + lr)*264 + ks*32 + q*8);
#pragma unroll
      for (int bb=0;bb<2;++bb)
        bv[bb] = *(const f16x8*)(Vb + (size_t)(vcb + 16*bb + lr)*2048 + jg + ks*32 + q*8);
#pragma unroll
      for (int a=0;a<2;++a)
#pragma unroll
        for (int bb=0;bb<2;++bb)
          Oacc[p][a][bb] = __builtin_amdgcn_mfma_f32_16x16x32_f16(ae[a], bv[bb], Oacc[p][a][bb], 0,0,0);
    }
    __syncthreads();                            // B3: El reads done before pass 1
  }

#pragma unroll
  for (int p=0;p<2;++p)
#pragma unroll
    for (int a=0;a<2;++a)
#pragma unroll
      for (int bb=0;bb<2;++bb)
#pragma unroll
        for (int r=0;r<4;++r){
          int row = 64*p + 32*(w&1) + 16*a + 4*q + r;
          int col = 32*(w>>1) + 16*bb + lr;
          Op[((size_t)bid*128 + row)*64 + col] = (f16)Oacc[p][a][bb][r];
        }
}

// ---------------- kernel 3: combine the 8 j-slice partials -----------------
// Grid 512: 32 rows per WG. Partial i for output block (nb,b) lives at
// k_attn bid = nb*64 + i*8 + b (matches k_attn decode).
__global__ void k_comb(const f16* __restrict__ Op, const float* __restrict__ mp,
                       const float* __restrict__ lp, float* __restrict__ out){
  const int rb = blockIdx.x >> 2;               // 0..127 = nb*8 + b
  const int qr = blockIdx.x & 3;                // row quarter
  const int b = rb & 7, nb = rb >> 3;
  const int pb = nb*64 + b;                     // partial i at pb + i*8
  const int t = threadIdx.x;
  const int row = qr*32 + (t >> 3);             // 32 rows x 8 col-groups
  const int c0 = (t & 7)*8;

  float m_[8], a_[8];
  float M = -1e30f, den = 0.f;
#pragma unroll
  for (int i=0;i<8;++i){ m_[i] = mp[(pb + i*8)*128 + row]; M = fmaxf(M, m_[i]); }
#pragma unroll
  for (int i=0;i<8;++i){ a_[i] = __expf(m_[i] - M); den += a_[i]*lp[(pb + i*8)*128 + row]; }
  float inv = 1.0f / den;

  float o[8] = {};
#pragma unroll
  for (int i=0;i<8;++i){
    f16x8 v = *(const f16x8*)(Op + ((size_t)(pb + i*8)*128 + row)*64 + c0);
#pragma unroll
    for (int e=0;e<8;++e) o[e] += a_[i]*(float)v[e];
  }
  float4 o0, o1;
  o0.x=o[0]*inv; o0.y=o[1]*inv; o0.z=o[2]*inv; o0.w=o[3]*inv;
  o1.x=o[4]*inv; o1.y=o[5]*inv; o1.z=o[6]*inv; o1.w=o[7]*inv;
  float* dst = out + ((size_t)b*2048 + nb*128 + row)*64 + c0;
  *(float4*)dst = o0;
  *(float4*)(dst+4) = o1;
}

extern "C" void kernel_launch(void* const* d_in, const int* in_sizes, int n_in,
                              void* d_out, int out_size, void* d_ws, size_t ws_size,
                              hipStream_t stream){
  (void)in_sizes; (void)n_in; (void)out_size; (void)ws_size;
  const float* Q  = (const float*)d_in[0];
  const float* K  = (const float*)d_in[1];
  const float* V  = (const float*)d_in[2];
  const float* Dm = (const float*)d_in[3];
  float* out = (float*)d_out;
  char* ws = (char*)d_ws;
  f16* Ph  = (f16*)ws;                                   // 64 MB
  f16* RhT = (f16*)(ws + (size_t)64*1024*1024);          //  8 MB
  f16* VhT = (f16*)(ws + (size_t)72*1024*1024);          //  2 MB
  f16* Op  = (f16*)(ws + (size_t)74*1024*1024);          // 16 MB (1024*128*64 f16)
  float* mpp = (float*)(ws + (size_t)90*1024*1024);      // 512 KB
  float* lpp = mpp + 1024*128;                           // 512 KB

  k_qk   <<<dim3(3328), 256, 0, stream>>>(Q, K, V, Dm, Ph, RhT, VhT);
  k_attn <<<dim3(1024), 256, 0, stream>>>(Ph, RhT, VhT, Op, mpp, lpp);
  k_comb <<<dim3(512),  256, 0, stream>>>(Op, mpp, lpp, out);
}